// Round 4
// baseline (779.046 us; speedup 1.0000x reference)
//
#include <hip/hip_runtime.h>
#include <hip/hip_bf16.h>
#include <cstdint>

namespace {

constexpr int Bn = 2, Sn = 2048, Hn = 3072, NQn = 24, NKVn = 8, HDn = 128;
constexpr int LDQKV = NQn * HDn + 2 * NKVn * HDn;  // 5120
constexpr int KCOLo = NQn * HDn;                   // 3072
constexpr int VCOLo = KCOLo + NKVn * HDn;          // 4096

typedef __attribute__((ext_vector_type(8))) __bf16 bf16x8;
typedef __attribute__((ext_vector_type(4))) float f32x4;
typedef __attribute__((ext_vector_type(8))) unsigned short u16x8;
typedef __attribute__((ext_vector_type(4))) unsigned short u16x4;

__device__ __forceinline__ unsigned short f2bf(float f) {
  union { float f; unsigned u; } v; v.f = f;
  return (unsigned short)((v.u + 0x7fffu + ((v.u >> 16) & 1u)) >> 16);
}
__device__ __forceinline__ float bf2f(unsigned short u) {
  union { unsigned u; float f; } v; v.u = ((unsigned)u) << 16;
  return v.f;
}
__device__ __forceinline__ void gload_lds16(const void* g, void* l) {
  __builtin_amdgcn_global_load_lds(
      (__attribute__((address_space(1))) void*)(uintptr_t)g,
      (__attribute__((address_space(3))) void*)(uintptr_t)l, 16, 0, 0);
}

// ---------------- RoPE cos/sin table: [S][48] each ----------------
__global__ void build_rope_tab(float* __restrict__ cosT, float* __restrict__ sinT) {
  int idx = blockIdx.x * 256 + threadIdx.x;
  if (idx >= Sn * 48) return;
  int s = idx / 48, i = idx % 48;
  // inv_freq = 10000^(-i/48) = exp2(-i * log2(10000)/48)
  float invf = exp2f(-(float)i * (13.287712379549449f / 48.f));
  float f = (float)s * invf;
  cosT[idx] = cosf(f);
  sinT[idx] = sinf(f);
}

// ---------------- f32 -> bf16 elementwise ----------------
__global__ void cvt_f32_bf16(const float* __restrict__ in, unsigned short* __restrict__ out, int n) {
  int i = (blockIdx.x * 256 + threadIdx.x) * 4;
  int stride = gridDim.x * 256 * 4;
  for (; i < n; i += stride) {
    float4 v = *(const float4*)&in[i];
    u16x4 o;
    o[0] = f2bf(v.x); o[1] = f2bf(v.y); o[2] = f2bf(v.z); o[3] = f2bf(v.w);
    *(u16x4*)&out[i] = o;
  }
}

// ---------------- transpose + convert: in f32 [K][N] -> out bf16 [N][K] ----------------
__global__ void transpose_cvt(const float* __restrict__ in, unsigned short* __restrict__ out,
                              int K, int N) {
  __shared__ float tile[32][33];
  int bx = blockIdx.x * 32;  // N
  int by = blockIdx.y * 32;  // K
  int tx = threadIdx.x & 31, ty = threadIdx.x >> 5;
#pragma unroll
  for (int r = ty; r < 32; r += 8)
    tile[r][tx] = in[(size_t)(by + r) * N + bx + tx];
  __syncthreads();
#pragma unroll
  for (int r = ty; r < 32; r += 8)
    out[(size_t)(bx + r) * K + by + tx] = f2bf(tile[tx][r]);
}

// ---------------- TN GEMM: C[M][N] = A[M][K] * B[N][K]^T  (m97 structure) ----------------
template <int BF16OUT>
__launch_bounds__(256, 2)
__global__ void gemm_tn(const unsigned short* __restrict__ A, const unsigned short* __restrict__ Bm,
                        void* __restrict__ Cout, int M, int N, int K) {
  __shared__ unsigned short Atile[128 * 32];
  __shared__ unsigned short Btile[128 * 32];
  const int t = threadIdx.x;
  const int lane = t & 63, w = t >> 6;
  const int wr = w >> 1, wc = w & 1;
  const int brow = blockIdx.y * 128, bcol = blockIdx.x * 128;
  f32x4 acc[4][4] = {};
  const int nK = K >> 5;
  const int r0 = t >> 2, ko0 = (t & 3) * 8;  // chunk t ; chunk t+256 -> r0+64 same ko0
  const unsigned short* Ab = A + (size_t)brow * K;
  const unsigned short* Bb = Bm + (size_t)bcol * K;
  char* Al0 = (char*)Atile + w * 1024;
  char* Al1 = (char*)Atile + 4096 + w * 1024;
  char* Bl0 = (char*)Btile + w * 1024;
  char* Bl1 = (char*)Btile + 4096 + w * 1024;
  const int l15 = lane & 15, lk = (lane >> 4) * 8;

  for (int kt = 0; kt < nK; ++kt) {
    const int k0 = kt * 32;
    __syncthreads();
    gload_lds16(Ab + (size_t)r0 * K + k0 + ko0, Al0);
    gload_lds16(Ab + (size_t)(r0 + 64) * K + k0 + ko0, Al1);
    gload_lds16(Bb + (size_t)r0 * K + k0 + ko0, Bl0);
    gload_lds16(Bb + (size_t)(r0 + 64) * K + k0 + ko0, Bl1);
    __syncthreads();
    bf16x8 aF[4], bF[4];
#pragma unroll
    for (int m = 0; m < 4; ++m)
      aF[m] = *(const bf16x8*)&Atile[(wr * 64 + m * 16 + l15) * 32 + lk];
#pragma unroll
    for (int n = 0; n < 4; ++n)
      bF[n] = *(const bf16x8*)&Btile[(wc * 64 + n * 16 + l15) * 32 + lk];
#pragma unroll
    for (int m = 0; m < 4; ++m)
#pragma unroll
      for (int n = 0; n < 4; ++n)
        acc[m][n] = __builtin_amdgcn_mfma_f32_16x16x32_bf16(aF[m], bF[n], acc[m][n], 0, 0, 0);
  }
  const int lr = (lane >> 4) * 4, lc = lane & 15;
  if (BF16OUT) {
    unsigned short* C = (unsigned short*)Cout;
#pragma unroll
    for (int m = 0; m < 4; ++m) {
      int row = brow + wr * 64 + m * 16 + lr;
#pragma unroll
      for (int n = 0; n < 4; ++n) {
        int col = bcol + wc * 64 + n * 16 + lc;
#pragma unroll
        for (int i = 0; i < 4; ++i)
          C[(size_t)(row + i) * N + col] = f2bf(acc[m][n][i]);
      }
    }
  } else {
    float* C = (float*)Cout;
#pragma unroll
    for (int m = 0; m < 4; ++m) {
      int row = brow + wr * 64 + m * 16 + lr;
#pragma unroll
      for (int n = 0; n < 4; ++n) {
        int col = bcol + wc * 64 + n * 16 + lc;
#pragma unroll
        for (int i = 0; i < 4; ++i)
          C[(size_t)(row + i) * N + col] = acc[m][n][i];
      }
    }
  }
}

// ---------------- RoPE in place on QKV [4096][5120] ----------------
__global__ void rope_kernel(unsigned short* __restrict__ QKV, const float* __restrict__ cosT,
                            const float* __restrict__ sinT) {
  int rid = blockIdx.x;  // 0..4095 = b*2048+s
  int s = rid & (Sn - 1);
  unsigned short* row = QKV + (size_t)rid * LDQKV;
  for (int p = threadIdx.x; p < 32 * 48; p += 256) {
    int h = p / 48, i = p % 48;
    int col = (h < NQn) ? h * HDn : KCOLo + (h - NQn) * HDn;
    float c = cosT[s * 48 + i], sn = sinT[s * 48 + i];
    float x1 = bf2f(row[col + i]), x2 = bf2f(row[col + i + 48]);
    row[col + i] = f2bf(x1 * c - x2 * sn);
    row[col + i + 48] = f2bf(x2 * c + x1 * sn);
  }
}

// ---------------- Flash attention (causal, GQA 3:1) ----------------
// grid: (S/64, B*NQ); 256 thr = 4 waves; wave w owns q rows [bq*64+w*16, +16)
__launch_bounds__(256, 2)
__global__ void attn_kernel(const unsigned short* __restrict__ QKV, unsigned short* __restrict__ O) {
  __shared__ unsigned short Klds[64 * 128];   // [kcol][hd] chunks XOR-swizzled by kcol&7
  __shared__ unsigned short Vlds[128 * 64];   // [hd][k]  chunks XOR-swizzled
  __shared__ unsigned short Plds[4][16 * 64]; // per-wave [q][k] swizzled
  const int t = threadIdx.x, lane = t & 63, w = t >> 6;
  const int bq = blockIdx.x;
  const int hid = blockIdx.y;
  const int b = hid / NQn, u = hid % NQn, kv = u / 3;
  const int l15 = lane & 15, lh = lane >> 4;

  bf16x8 qf[4];
  {
    int qrow = bq * 64 + w * 16 + l15;
    const unsigned short* qp = QKV + (size_t)(b * Sn + qrow) * LDQKV + u * HDn;
#pragma unroll
    for (int f = 0; f < 4; ++f) qf[f] = *(const bf16x8*)(qp + f * 32 + lh * 8);
  }
  float mrow[4], lrow[4];
  f32x4 Oa[8] = {};
#pragma unroll
  for (int i = 0; i < 4; ++i) { mrow[i] = -1e30f; lrow[i] = 0.f; }
  const float cscale = 0.08838834764831845f * 1.4426950408889634f;  // 1/sqrt(128)*log2e

  const unsigned short* Kg = QKV + (size_t)(b * Sn) * LDQKV + KCOLo + kv * HDn;
  const unsigned short* Vg = QKV + (size_t)(b * Sn) * LDQKV + VCOLo + kv * HDn;

  for (int kt = 0; kt <= bq; ++kt) {
    __syncthreads();  // prior tile's LDS reads complete
    // K stage: linear LDS writes, source pre-swizzled so reads are conflict-light
#pragma unroll
    for (int iter = 0; iter < 4; ++iter) {
      int c = iter * 256 + t;
      int krow = c >> 4, pch = c & 15;
      int hch = (pch & 8) | ((pch & 7) ^ (krow & 7));
      gload_lds16(Kg + (size_t)(kt * 64 + krow) * LDQKV + hch * 8,
                  (char*)Klds + (iter * 256 + w * 64) * 16);
    }
    // V stage: transpose+swizzle through registers
    u16x8 vtmp[4];
#pragma unroll
    for (int iter = 0; iter < 4; ++iter) {
      int c = iter * 256 + t;
      vtmp[iter] = *(const u16x8*)(Vg + (size_t)(kt * 64 + (c >> 4)) * LDQKV + (c & 15) * 8);
    }
#pragma unroll
    for (int iter = 0; iter < 4; ++iter) {
      int c = iter * 256 + t;
      int r = c >> 4, hd0 = (c & 15) * 8;
#pragma unroll
      for (int j = 0; j < 8; ++j) {
        int hd = hd0 + j;
        int f = (hd & 7) ^ ((hd >> 3) & 7);
        int pos = ((r >> 3) ^ f) & 7;
        Vlds[hd * 64 + pos * 8 + (r & 7)] = vtmp[iter][j];
      }
    }
    __syncthreads();
    // QK^T : S[q 16][k 64]
    f32x4 Sg[4] = {};
#pragma unroll
    for (int g = 0; g < 4; ++g) {
      int kcol = g * 16 + l15;
#pragma unroll
      for (int s = 0; s < 4; ++s) {
        int h = s * 4 + lh;
        int p = (h & 8) | ((h & 7) ^ (kcol & 7));
        bf16x8 kf = *(const bf16x8*)&Klds[kcol * 128 + p * 8];
        Sg[g] = __builtin_amdgcn_mfma_f32_16x16x32_bf16(qf[s], kf, Sg[g], 0, 0, 0);
      }
    }
    float P[4][4];
    const bool last = (kt == bq);
#pragma unroll
    for (int g = 0; g < 4; ++g)
#pragma unroll
      for (int i = 0; i < 4; ++i) {
        float sv = Sg[g][i] * cscale;
        if (last) {
          int colw = g * 16 + l15;
          int roww = w * 16 + lh * 4 + i;
          if (colw > roww) sv = -1e30f;
        }
        P[g][i] = sv;
      }
    float rs[4];
#pragma unroll
    for (int i = 0; i < 4; ++i) {
      float pm = fmaxf(fmaxf(P[0][i], P[1][i]), fmaxf(P[2][i], P[3][i]));
#pragma unroll
      for (int msk = 1; msk < 16; msk <<= 1) pm = fmaxf(pm, __shfl_xor(pm, msk, 64));
      float mn = fmaxf(mrow[i], pm);
      rs[i] = exp2f(mrow[i] - mn);
      mrow[i] = mn;
      float ps = 0.f;
#pragma unroll
      for (int g = 0; g < 4; ++g) { float e = exp2f(P[g][i] - mn); P[g][i] = e; ps += e; }
#pragma unroll
      for (int msk = 1; msk < 16; msk <<= 1) ps += __shfl_xor(ps, msk, 64);
      lrow[i] = lrow[i] * rs[i] + ps;
    }
#pragma unroll
    for (int g = 0; g < 8; ++g)
#pragma unroll
      for (int i = 0; i < 4; ++i) Oa[g][i] *= rs[i];
    // P -> per-wave LDS (swizzled), then PV
    unsigned short* pl = Plds[w];
#pragma unroll
    for (int g = 0; g < 4; ++g) {
      int k = g * 16 + l15, ch = k >> 3;
#pragma unroll
      for (int i = 0; i < 4; ++i) {
        int q = lh * 4 + i;
        int pos = (ch ^ (q & 7)) & 7;
        pl[q * 64 + pos * 8 + (k & 7)] = f2bf(P[g][i]);
      }
    }
#pragma unroll
    for (int kk = 0; kk < 2; ++kk) {
      int ch = kk * 4 + lh;
      int posp = (ch ^ (l15 & 7)) & 7;
      bf16x8 pf = *(const bf16x8*)&pl[l15 * 64 + posp * 8];
#pragma unroll
      for (int g = 0; g < 8; ++g) {
        int hd = g * 16 + l15;
        int f = (hd & 7) ^ ((hd >> 3) & 7);
        int vpos = (ch ^ f) & 7;
        bf16x8 vf = *(const bf16x8*)&Vlds[hd * 64 + vpos * 8];
        Oa[g] = __builtin_amdgcn_mfma_f32_16x16x32_bf16(pf, vf, Oa[g], 0, 0, 0);
      }
    }
  }
#pragma unroll
  for (int i = 0; i < 4; ++i) {
    float inv = 1.0f / lrow[i];
    int qrow = bq * 64 + w * 16 + lh * 4 + i;
    unsigned short* op = O + (size_t)(b * Sn + qrow) * (NQn * HDn) + u * HDn;
#pragma unroll
    for (int g = 0; g < 8; ++g) op[g * 16 + l15] = f2bf(Oa[g][i] * inv);
  }
}

}  // namespace

extern "C" void kernel_launch(void* const* d_in, const int* in_sizes, int n_in,
                              void* d_out, int out_size, void* d_ws, size_t ws_size,
                              hipStream_t stream) {
  const float* hidden = (const float*)d_in[0];
  // d_in[1] = attention_mask (causal tril) -- implemented analytically
  const float* Wq = (const float*)d_in[2];
  const float* Wk = (const float*)d_in[3];
  const float* Wv = (const float*)d_in[4];
  const float* Wo = (const float*)d_in[5];
  float* out = (float*)d_out;

  // Workspace layout (aliased to minimize footprint; same-stream ordering
  // makes each alias safe):
  //   [0)                Xb   (bf16 hidden, 25.2MB)  -- dead after GEMM1
  //                      Obuf (bf16 attn out, 25.2MB) aliases Xb
  //   [szXb)             Wqkv (bf16 B^T, 31.5MB)     -- dead after GEMM1
  //                      Wob  (bf16 B^T, 18.9MB) aliases Wqkv (transposed AFTER GEMM1)
  //   [szXb+szWqkv)      QKV  (bf16, 41.9MB)
  //   [... + szQKV)      cosT/sinT tables (0.8MB)
  char* ws = (char*)d_ws;
  constexpr size_t szXb = (size_t)Bn * Sn * Hn * 2;            // 25165824
  constexpr size_t szWqkv = (size_t)LDQKV * Hn * 2;            // 31457280
  constexpr size_t szQKV = (size_t)Bn * Sn * LDQKV * 2;        // 41943040
  constexpr size_t szTab = (size_t)Sn * 48 * 4;                // 393216
  constexpr size_t szTotal = szXb + szWqkv + szQKV + 2 * szTab; // 99352576
  if (ws_size < szTotal) return;  // insufficient workspace: fail cleanly, don't fault

  unsigned short* Xb = (unsigned short*)(ws);
  unsigned short* Obuf = Xb;  // alias: Xb dead after GEMM1
  unsigned short* Wqkv = (unsigned short*)(ws + szXb);
  unsigned short* Wob = Wqkv;  // alias: Wqkv dead after GEMM1; Wo transposed after
  unsigned short* QKV = (unsigned short*)(ws + szXb + szWqkv);
  float* cosT = (float*)(ws + szXb + szWqkv + szQKV);
  float* sinT = (float*)(ws + szXb + szWqkv + szQKV + szTab);

  build_rope_tab<<<(Sn * 48 + 255) / 256, 256, 0, stream>>>(cosT, sinT);
  cvt_f32_bf16<<<3072, 256, 0, stream>>>(hidden, Xb, Bn * Sn * Hn);
  transpose_cvt<<<dim3(96, 96), 256, 0, stream>>>(Wq, Wqkv, Hn, NQn * HDn);
  transpose_cvt<<<dim3(32, 96), 256, 0, stream>>>(Wk, Wqkv + (size_t)KCOLo * Hn, Hn, NKVn * HDn);
  transpose_cvt<<<dim3(32, 96), 256, 0, stream>>>(Wv, Wqkv + (size_t)VCOLo * Hn, Hn, NKVn * HDn);
  gemm_tn<1><<<dim3(LDQKV / 128, (Bn * Sn) / 128), 256, 0, stream>>>(Xb, Wqkv, QKV,
                                                                    Bn * Sn, LDQKV, Hn);
  // Wqkv and Xb are now dead; reuse their space.
  transpose_cvt<<<dim3(96, 96), 256, 0, stream>>>(Wo, Wob, Hn, Hn);
  rope_kernel<<<Bn * Sn, 256, 0, stream>>>(QKV, cosT, sinT);
  attn_kernel<<<dim3(Sn / 64, Bn * NQn), 256, 0, stream>>>(QKV, Obuf);
  gemm_tn<0><<<dim3(Hn / 128, (Bn * Sn) / 128), 256, 0, stream>>>(Obuf, Wob, out,
                                                                  Bn * Sn, Hn, Hn);
}

// Round 7
// 733.010 us; speedup vs baseline: 1.0628x; 1.0628x over previous
//
#include <hip/hip_runtime.h>
#include <hip/hip_bf16.h>
#include <cstdint>

namespace {

constexpr int Bn = 2, Sn = 2048, Hn = 3072, NQn = 24, NKVn = 8, HDn = 128;
constexpr int LDQKV = NQn * HDn + 2 * NKVn * HDn;  // 5120
constexpr int KCOLo = NQn * HDn;                   // 3072
constexpr int VCOLo = KCOLo + NKVn * HDn;          // 4096

typedef __attribute__((ext_vector_type(8))) __bf16 bf16x8;
typedef __attribute__((ext_vector_type(4))) float f32x4;
typedef __attribute__((ext_vector_type(4))) unsigned short u16x4;

__device__ __forceinline__ unsigned short f2bf(float f) {
  union { float f; unsigned u; } v; v.f = f;
  return (unsigned short)((v.u + 0x7fffu + ((v.u >> 16) & 1u)) >> 16);
}
__device__ __forceinline__ float bf2f(unsigned short u) {
  union { unsigned u; float f; } v; v.u = ((unsigned)u) << 16;
  return v.f;
}
__device__ __forceinline__ void gload_lds16(const void* g, void* l) {
  __builtin_amdgcn_global_load_lds(
      (__attribute__((address_space(1))) void*)(uintptr_t)g,
      (__attribute__((address_space(3))) void*)(uintptr_t)l, 16, 0, 0);
}

// ---------------- RoPE cos/sin table: [S][48] each ----------------
__global__ void build_rope_tab(float* __restrict__ cosT, float* __restrict__ sinT) {
  int idx = blockIdx.x * 256 + threadIdx.x;
  if (idx >= Sn * 48) return;
  int s = idx / 48, i = idx % 48;
  float invf = exp2f(-(float)i * (13.287712379549449f / 48.f));
  float f = (float)s * invf;
  cosT[idx] = cosf(f);
  sinT[idx] = sinf(f);
}

// ---------------- f32 -> bf16 elementwise ----------------
__global__ void cvt_f32_bf16(const float* __restrict__ in, unsigned short* __restrict__ out, int n) {
  int i = (blockIdx.x * 256 + threadIdx.x) * 4;
  int stride = gridDim.x * 256 * 4;
  for (; i < n; i += stride) {
    float4 v = *(const float4*)&in[i];
    u16x4 o;
    o[0] = f2bf(v.x); o[1] = f2bf(v.y); o[2] = f2bf(v.z); o[3] = f2bf(v.w);
    *(u16x4*)&out[i] = o;
  }
}

// ---------------- transpose + convert: in f32 [K][N] -> out bf16 [N][K] ----------------
__global__ void transpose_cvt(const float* __restrict__ in, unsigned short* __restrict__ out,
                              int K, int N) {
  __shared__ float tile[32][33];
  int bx = blockIdx.x * 32;  // N
  int by = blockIdx.y * 32;  // K
  int tx = threadIdx.x & 31, ty = threadIdx.x >> 5;
#pragma unroll
  for (int r = ty; r < 32; r += 8)
    tile[r][tx] = in[(size_t)(by + r) * N + bx + tx];
  __syncthreads();
#pragma unroll
  for (int r = ty; r < 32; r += 8)
    out[(size_t)(bx + r) * K + by + tx] = f2bf(tile[tx][r]);
}

// ---------------- V pre-transpose: QKV V-cols -> VT[(b*NKV+kv)*HD + hd][s] ----------------
__global__ void transpose_v(const unsigned short* __restrict__ QKV, unsigned short* __restrict__ VT) {
  __shared__ unsigned short tile[32][33];
  int s0 = blockIdx.x * 32;
  int b = blockIdx.y >> 5;
  int vc0 = (blockIdx.y & 31) * 32;  // 0..992 within the 1024 V cols of batch b
  int tx = threadIdx.x & 31, ty = threadIdx.x >> 5;
#pragma unroll
  for (int r = ty; r < 32; r += 8)
    tile[r][tx] = QKV[(size_t)(b * Sn + s0 + r) * LDQKV + VCOLo + vc0 + tx];
  __syncthreads();
#pragma unroll
  for (int r = ty; r < 32; r += 8)
    VT[(size_t)(b * (NKVn * HDn) + vc0 + r) * Sn + s0 + tx] = tile[tx][r];
}

// ---------------- TN GEMM: C[M][N] = A[M][K] * B[N][K]^T  (m97 structure) ----------------
template <int BF16OUT>
__launch_bounds__(256, 2)
__global__ void gemm_tn(const unsigned short* __restrict__ A, const unsigned short* __restrict__ Bm,
                        void* __restrict__ Cout, int M, int N, int K) {
  __shared__ unsigned short Atile[128 * 32];
  __shared__ unsigned short Btile[128 * 32];
  const int t = threadIdx.x;
  const int lane = t & 63, w = t >> 6;
  const int wr = w >> 1, wc = w & 1;
  const int brow = blockIdx.y * 128, bcol = blockIdx.x * 128;
  f32x4 acc[4][4] = {};
  const int nK = K >> 5;
  const int r0 = t >> 2, ko0 = (t & 3) * 8;
  const unsigned short* Ab = A + (size_t)brow * K;
  const unsigned short* Bb = Bm + (size_t)bcol * K;
  char* Al0 = (char*)Atile + w * 1024;
  char* Al1 = (char*)Atile + 4096 + w * 1024;
  char* Bl0 = (char*)Btile + w * 1024;
  char* Bl1 = (char*)Btile + 4096 + w * 1024;
  const int l15 = lane & 15, lk = (lane >> 4) * 8;

  for (int kt = 0; kt < nK; ++kt) {
    const int k0 = kt * 32;
    __syncthreads();
    gload_lds16(Ab + (size_t)r0 * K + k0 + ko0, Al0);
    gload_lds16(Ab + (size_t)(r0 + 64) * K + k0 + ko0, Al1);
    gload_lds16(Bb + (size_t)r0 * K + k0 + ko0, Bl0);
    gload_lds16(Bb + (size_t)(r0 + 64) * K + k0 + ko0, Bl1);
    __syncthreads();
    bf16x8 aF[4], bF[4];
#pragma unroll
    for (int m = 0; m < 4; ++m)
      aF[m] = *(const bf16x8*)&Atile[(wr * 64 + m * 16 + l15) * 32 + lk];
#pragma unroll
    for (int n = 0; n < 4; ++n)
      bF[n] = *(const bf16x8*)&Btile[(wc * 64 + n * 16 + l15) * 32 + lk];
#pragma unroll
    for (int m = 0; m < 4; ++m)
#pragma unroll
      for (int n = 0; n < 4; ++n)
        acc[m][n] = __builtin_amdgcn_mfma_f32_16x16x32_bf16(aF[m], bF[n], acc[m][n], 0, 0, 0);
  }
  const int lr = (lane >> 4) * 4, lc = lane & 15;
  if (BF16OUT) {
    unsigned short* C = (unsigned short*)Cout;
#pragma unroll
    for (int m = 0; m < 4; ++m) {
      int row = brow + wr * 64 + m * 16 + lr;
#pragma unroll
      for (int n = 0; n < 4; ++n) {
        int col = bcol + wc * 64 + n * 16 + lc;
#pragma unroll
        for (int i = 0; i < 4; ++i)
          C[(size_t)(row + i) * N + col] = f2bf(acc[m][n][i]);
      }
    }
  } else {
    float* C = (float*)Cout;
#pragma unroll
    for (int m = 0; m < 4; ++m) {
      int row = brow + wr * 64 + m * 16 + lr;
#pragma unroll
      for (int n = 0; n < 4; ++n) {
        int col = bcol + wc * 64 + n * 16 + lc;
#pragma unroll
        for (int i = 0; i < 4; ++i)
          C[(size_t)(row + i) * N + col] = acc[m][n][i];
      }
    }
  }
}

// ---------------- RoPE in place on QKV [4096][5120] ----------------
__global__ void rope_kernel(unsigned short* __restrict__ QKV, const float* __restrict__ cosT,
                            const float* __restrict__ sinT) {
  int rid = blockIdx.x;
  int s = rid & (Sn - 1);
  unsigned short* row = QKV + (size_t)rid * LDQKV;
  for (int p = threadIdx.x; p < 32 * 48; p += 256) {
    int h = p / 48, i = p % 48;
    int col = (h < NQn) ? h * HDn : KCOLo + (h - NQn) * HDn;
    float c = cosT[s * 48 + i], sn = sinT[s * 48 + i];
    float x1 = bf2f(row[col + i]), x2 = bf2f(row[col + i + 48]);
    row[col + i] = f2bf(x1 * c - x2 * sn);
    row[col + i + 48] = f2bf(x2 * c + x1 * sn);
  }
}

// ---------------- Flash attention (causal, GQA 3:1), double-buffered K/V ----------------
// grid: (S/64, B*NQ); 256 thr = 4 waves; wave w owns q rows [bq*64+w*16, +16)
__launch_bounds__(256, 2)
__global__ void attn_kernel(const unsigned short* __restrict__ QKV,
                            const unsigned short* __restrict__ VT,
                            unsigned short* __restrict__ O) {
  __shared__ unsigned short Klds[2][64 * 128];  // [kcol][hd] chunks, src pre-swizzled
  __shared__ unsigned short Vlds[2][128 * 64];  // [hd][k] chunks, src pre-swizzled
  __shared__ unsigned short Plds[4][16 * 64];   // per-wave [q][k] swizzled
  const int t = threadIdx.x, lane = t & 63, w = t >> 6;
  const int bq = gridDim.x - 1 - blockIdx.x;  // heavy (many-tile) blocks dispatch first
  const int hid = blockIdx.y;
  const int b = hid / NQn, u = hid % NQn, kv = u / 3;
  const int l15 = lane & 15, lh = lane >> 4;

  bf16x8 qf[4];
  {
    int qrow = bq * 64 + w * 16 + l15;
    const unsigned short* qp = QKV + (size_t)(b * Sn + qrow) * LDQKV + u * HDn;
#pragma unroll
    for (int f = 0; f < 4; ++f) qf[f] = *(const bf16x8*)(qp + f * 32 + lh * 8);
  }
  float mrow[4], lrow[4];
  f32x4 Oa[8] = {};
#pragma unroll
  for (int i = 0; i < 4; ++i) { mrow[i] = -1e30f; lrow[i] = 0.f; }
  const float cscale = 0.08838834764831845f * 1.4426950408889634f;  // 1/sqrt(128)*log2e

  const unsigned short* Kg = QKV + (size_t)(b * Sn) * LDQKV + KCOLo + kv * HDn;
  const unsigned short* Vg = VT + (size_t)(b * NKVn + kv) * HDn * Sn;

  auto stageK = [&](int kt, int buf) {
#pragma unroll
    for (int iter = 0; iter < 4; ++iter) {
      int c = iter * 256 + t;
      int krow = c >> 4, pch = c & 15;
      int hch = (pch & 8) | ((pch & 7) ^ (krow & 7));
      gload_lds16(Kg + (size_t)(kt * 64 + krow) * LDQKV + hch * 8,
                  (char*)&Klds[buf][0] + (iter * 256 + w * 64) * 16);
    }
  };
  auto stageV = [&](int kt, int buf) {
#pragma unroll
    for (int iter = 0; iter < 4; ++iter) {
      int c = iter * 256 + t;
      int hd = c >> 3, p = c & 7;
      int sch = p ^ (hd & 7);
      gload_lds16(Vg + (size_t)hd * Sn + kt * 64 + sch * 8,
                  (char*)&Vlds[buf][0] + (iter * 256 + w * 64) * 16);
    }
  };

  const int nt = bq + 1;
  stageK(0, 0);
  stageV(0, 0);
  __syncthreads();  // drains vmcnt (barrier semantics)

  for (int kt = 0; kt < nt; ++kt) {
    const int cur = kt & 1;
    if (kt + 1 < nt) { stageK(kt + 1, cur ^ 1); stageV(kt + 1, cur ^ 1); }
    const unsigned short* Kb = &Klds[cur][0];
    const unsigned short* Vb = &Vlds[cur][0];
    // QK^T : S[q 16][k 64]
    f32x4 Sg[4] = {};
    __builtin_amdgcn_s_setprio(1);
#pragma unroll
    for (int g = 0; g < 4; ++g) {
      int kcol = g * 16 + l15;
#pragma unroll
      for (int s = 0; s < 4; ++s) {
        int h = s * 4 + lh;
        int p = (h & 8) | ((h & 7) ^ (kcol & 7));
        bf16x8 kf = *(const bf16x8*)&Kb[kcol * 128 + p * 8];
        Sg[g] = __builtin_amdgcn_mfma_f32_16x16x32_bf16(qf[s], kf, Sg[g], 0, 0, 0);
      }
    }
    __builtin_amdgcn_s_setprio(0);
    float P[4][4];
    const bool last = (kt == bq);
#pragma unroll
    for (int g = 0; g < 4; ++g)
#pragma unroll
      for (int i = 0; i < 4; ++i) {
        float sv = Sg[g][i] * cscale;
        if (last) {
          int colw = g * 16 + l15;
          int roww = w * 16 + lh * 4 + i;
          if (colw > roww) sv = -1e30f;
        }
        P[g][i] = sv;
      }
    float rs[4];
#pragma unroll
    for (int i = 0; i < 4; ++i) {
      float pm = fmaxf(fmaxf(P[0][i], P[1][i]), fmaxf(P[2][i], P[3][i]));
#pragma unroll
      for (int msk = 1; msk < 16; msk <<= 1) pm = fmaxf(pm, __shfl_xor(pm, msk, 64));
      float mn = fmaxf(mrow[i], pm);
      rs[i] = exp2f(mrow[i] - mn);
      mrow[i] = mn;
      float ps = 0.f;
#pragma unroll
      for (int g = 0; g < 4; ++g) { float e = exp2f(P[g][i] - mn); P[g][i] = e; ps += e; }
#pragma unroll
      for (int msk = 1; msk < 16; msk <<= 1) ps += __shfl_xor(ps, msk, 64);
      lrow[i] = lrow[i] * rs[i] + ps;
    }
#pragma unroll
    for (int g = 0; g < 8; ++g)
#pragma unroll
      for (int i = 0; i < 4; ++i) Oa[g][i] *= rs[i];
    // P -> per-wave LDS (swizzled), then PV
    unsigned short* pl = Plds[w];
#pragma unroll
    for (int g = 0; g < 4; ++g) {
      int k = g * 16 + l15, ch = k >> 3;
#pragma unroll
      for (int i = 0; i < 4; ++i) {
        int q = lh * 4 + i;
        int pos = (ch ^ (q & 7)) & 7;
        pl[q * 64 + pos * 8 + (k & 7)] = f2bf(P[g][i]);
      }
    }
    __builtin_amdgcn_s_setprio(1);
#pragma unroll
    for (int kk = 0; kk < 2; ++kk) {
      int ch = kk * 4 + lh;
      int posp = (ch ^ (l15 & 7)) & 7;
      bf16x8 pf = *(const bf16x8*)&pl[l15 * 64 + posp * 8];
#pragma unroll
      for (int g = 0; g < 8; ++g) {
        int hd = g * 16 + l15;
        int vpos = (ch ^ (hd & 7)) & 7;
        bf16x8 vf = *(const bf16x8*)&Vb[hd * 64 + vpos * 8];
        Oa[g] = __builtin_amdgcn_mfma_f32_16x16x32_bf16(pf, vf, Oa[g], 0, 0, 0);
      }
    }
    __builtin_amdgcn_s_setprio(0);
    __syncthreads();  // all waves done with buf cur; next-tile loads drained
  }
#pragma unroll
  for (int i = 0; i < 4; ++i) {
    float inv = 1.0f / lrow[i];
    int qrow = bq * 64 + w * 16 + lh * 4 + i;
    unsigned short* op = O + (size_t)(b * Sn + qrow) * (NQn * HDn) + u * HDn;
#pragma unroll
    for (int g = 0; g < 8; ++g) op[g * 16 + l15] = f2bf(Oa[g][i] * inv);
  }
}

}  // namespace

extern "C" void kernel_launch(void* const* d_in, const int* in_sizes, int n_in,
                              void* d_out, int out_size, void* d_ws, size_t ws_size,
                              hipStream_t stream) {
  const float* hidden = (const float*)d_in[0];
  // d_in[1] = attention_mask (causal tril) -- implemented analytically
  const float* Wq = (const float*)d_in[2];
  const float* Wk = (const float*)d_in[3];
  const float* Wv = (const float*)d_in[4];
  const float* Wo = (const float*)d_in[5];
  float* out = (float*)d_out;

  // Workspace layout (aliased; same-stream ordering makes each alias safe):
  //   [0)           Xb   (25.2MB)  -- dead after GEMM1; Obuf aliases it
  //   [szXb)        Wqkv (31.5MB)  -- dead after GEMM1; Wob (18.9MB) + VT (8.4MB) alias it
  //   [szXb+szWqkv) QKV  (41.9MB)
  //   [+szQKV)      cosT/sinT (0.8MB)
  char* ws = (char*)d_ws;
  constexpr size_t szXb = (size_t)Bn * Sn * Hn * 2;             // 25165824
  constexpr size_t szWqkv = (size_t)LDQKV * Hn * 2;             // 31457280
  constexpr size_t szWo = (size_t)Hn * Hn * 2;                  // 18874368
  constexpr size_t szVT = (size_t)Bn * NKVn * HDn * Sn * 2;     // 8388608
  constexpr size_t szQKV = (size_t)Bn * Sn * LDQKV * 2;         // 41943040
  constexpr size_t szTab = (size_t)Sn * 48 * 4;                 // 393216
  static_assert(szWo + szVT <= szWqkv, "Wob+VT must fit in Wqkv region");
  constexpr size_t szTotal = szXb + szWqkv + szQKV + 2 * szTab; // 99352576
  if (ws_size < szTotal) return;  // fail cleanly, don't fault

  unsigned short* Xb = (unsigned short*)(ws);
  unsigned short* Obuf = Xb;                                  // alias
  unsigned short* Wqkv = (unsigned short*)(ws + szXb);
  unsigned short* Wob = Wqkv;                                 // alias (after GEMM1)
  unsigned short* VT = (unsigned short*)(ws + szXb + szWo);   // alias (after GEMM1)
  unsigned short* QKV = (unsigned short*)(ws + szXb + szWqkv);
  float* cosT = (float*)(ws + szXb + szWqkv + szQKV);
  float* sinT = (float*)(ws + szXb + szWqkv + szQKV + szTab);

  build_rope_tab<<<(Sn * 48 + 255) / 256, 256, 0, stream>>>(cosT, sinT);
  cvt_f32_bf16<<<3072, 256, 0, stream>>>(hidden, Xb, Bn * Sn * Hn);
  transpose_cvt<<<dim3(96, 96), 256, 0, stream>>>(Wq, Wqkv, Hn, NQn * HDn);
  transpose_cvt<<<dim3(32, 96), 256, 0, stream>>>(Wk, Wqkv + (size_t)KCOLo * Hn, Hn, NKVn * HDn);
  transpose_cvt<<<dim3(32, 96), 256, 0, stream>>>(Wv, Wqkv + (size_t)VCOLo * Hn, Hn, NKVn * HDn);
  gemm_tn<1><<<dim3(LDQKV / 128, (Bn * Sn) / 128), 256, 0, stream>>>(Xb, Wqkv, QKV,
                                                                    Bn * Sn, LDQKV, Hn);
  // Wqkv and Xb are now dead; reuse their space.
  transpose_cvt<<<dim3(96, 96), 256, 0, stream>>>(Wo, Wob, Hn, Hn);
  transpose_v<<<dim3(Sn / 32, Bn * NKVn * HDn / 32), 256, 0, stream>>>(QKV, VT);
  rope_kernel<<<Bn * Sn, 256, 0, stream>>>(QKV, cosT, sinT);
  attn_kernel<<<dim3(Sn / 64, Bn * NQn), 256, 0, stream>>>(QKV, VT, Obuf);
  gemm_tn<0><<<dim3(Hn / 128, (Bn * Sn) / 128), 256, 0, stream>>>(Obuf, Wob, out,
                                                                  Bn * Sn, Hn, Hn);
}

// Round 8
// 667.622 us; speedup vs baseline: 1.1669x; 1.0979x over previous
//
#include <hip/hip_runtime.h>
#include <hip/hip_bf16.h>
#include <cstdint>

namespace {

constexpr int Bn = 2, Sn = 2048, Hn = 3072, NQn = 24, NKVn = 8, HDn = 128;
constexpr int LDQKV = NQn * HDn + 2 * NKVn * HDn;  // 5120
constexpr int KCOLo = NQn * HDn;                   // 3072
constexpr int VCOLo = KCOLo + NKVn * HDn;          // 4096

typedef __attribute__((ext_vector_type(8))) __bf16 bf16x8;
typedef __attribute__((ext_vector_type(4))) float f32x4;
typedef __attribute__((ext_vector_type(4))) unsigned short u16x4;

__device__ __forceinline__ unsigned short f2bf(float f) {
  union { float f; unsigned u; } v; v.f = f;
  return (unsigned short)((v.u + 0x7fffu + ((v.u >> 16) & 1u)) >> 16);
}
__device__ __forceinline__ float bf2f(unsigned short u) {
  union { unsigned u; float f; } v; v.u = ((unsigned)u) << 16;
  return v.f;
}
__device__ __forceinline__ void gload_lds16(const void* g, void* l) {
  __builtin_amdgcn_global_load_lds(
      (__attribute__((address_space(1))) void*)(uintptr_t)g,
      (__attribute__((address_space(3))) void*)(uintptr_t)l, 16, 0, 0);
}

// ---------------- RoPE cos/sin table: [S][48] each ----------------
__global__ void build_rope_tab(float* __restrict__ cosT, float* __restrict__ sinT) {
  int idx = blockIdx.x * 256 + threadIdx.x;
  if (idx >= Sn * 48) return;
  int s = idx / 48, i = idx % 48;
  float invf = exp2f(-(float)i * (13.287712379549449f / 48.f));
  float f = (float)s * invf;
  cosT[idx] = cosf(f);
  sinT[idx] = sinf(f);
}

// ---------------- f32 -> bf16 elementwise ----------------
__global__ void cvt_f32_bf16(const float* __restrict__ in, unsigned short* __restrict__ out, int n) {
  int i = (blockIdx.x * 256 + threadIdx.x) * 4;
  int stride = gridDim.x * 256 * 4;
  for (; i < n; i += stride) {
    float4 v = *(const float4*)&in[i];
    u16x4 o;
    o[0] = f2bf(v.x); o[1] = f2bf(v.y); o[2] = f2bf(v.z); o[3] = f2bf(v.w);
    *(u16x4*)&out[i] = o;
  }
}

// ---------------- transpose + convert: in f32 [K][N] -> out bf16 [N][K] ----------------
__global__ void transpose_cvt(const float* __restrict__ in, unsigned short* __restrict__ out,
                              int K, int N) {
  __shared__ float tile[32][33];
  int bx = blockIdx.x * 32;  // N
  int by = blockIdx.y * 32;  // K
  int tx = threadIdx.x & 31, ty = threadIdx.x >> 5;
#pragma unroll
  for (int r = ty; r < 32; r += 8)
    tile[r][tx] = in[(size_t)(by + r) * N + bx + tx];
  __syncthreads();
#pragma unroll
  for (int r = ty; r < 32; r += 8)
    out[(size_t)(bx + r) * K + by + tx] = f2bf(tile[tx][r]);
}

// ---------------- V pre-transpose: QKV V-cols -> VT[(b*NKV+kv)*HD + hd][s] ----------------
__global__ void transpose_v(const unsigned short* __restrict__ QKV, unsigned short* __restrict__ VT) {
  __shared__ unsigned short tile[32][33];
  int s0 = blockIdx.x * 32;
  int b = blockIdx.y >> 5;
  int vc0 = (blockIdx.y & 31) * 32;  // 0..992 within the 1024 V cols of batch b
  int tx = threadIdx.x & 31, ty = threadIdx.x >> 5;
#pragma unroll
  for (int r = ty; r < 32; r += 8)
    tile[r][tx] = QKV[(size_t)(b * Sn + s0 + r) * LDQKV + VCOLo + vc0 + tx];
  __syncthreads();
#pragma unroll
  for (int r = ty; r < 32; r += 8)
    VT[(size_t)(b * (NKVn * HDn) + vc0 + r) * Sn + s0 + tx] = tile[tx][r];
}

// ---------------- TN GEMM: C[M][N] = A[M][K] * B[N][K]^T  (m97 structure) ----------------
template <int BF16OUT>
__launch_bounds__(256, 2)
__global__ void gemm_tn(const unsigned short* __restrict__ A, const unsigned short* __restrict__ Bm,
                        void* __restrict__ Cout, int M, int N, int K) {
  __shared__ unsigned short Atile[128 * 32];
  __shared__ unsigned short Btile[128 * 32];
  const int t = threadIdx.x;
  const int lane = t & 63, w = t >> 6;
  const int wr = w >> 1, wc = w & 1;
  const int brow = blockIdx.y * 128, bcol = blockIdx.x * 128;
  f32x4 acc[4][4] = {};
  const int nK = K >> 5;
  const int r0 = t >> 2, ko0 = (t & 3) * 8;
  const unsigned short* Ab = A + (size_t)brow * K;
  const unsigned short* Bb = Bm + (size_t)bcol * K;
  char* Al0 = (char*)Atile + w * 1024;
  char* Al1 = (char*)Atile + 4096 + w * 1024;
  char* Bl0 = (char*)Btile + w * 1024;
  char* Bl1 = (char*)Btile + 4096 + w * 1024;
  const int l15 = lane & 15, lk = (lane >> 4) * 8;

  for (int kt = 0; kt < nK; ++kt) {
    const int k0 = kt * 32;
    __syncthreads();
    gload_lds16(Ab + (size_t)r0 * K + k0 + ko0, Al0);
    gload_lds16(Ab + (size_t)(r0 + 64) * K + k0 + ko0, Al1);
    gload_lds16(Bb + (size_t)r0 * K + k0 + ko0, Bl0);
    gload_lds16(Bb + (size_t)(r0 + 64) * K + k0 + ko0, Bl1);
    __syncthreads();
    bf16x8 aF[4], bF[4];
#pragma unroll
    for (int m = 0; m < 4; ++m)
      aF[m] = *(const bf16x8*)&Atile[(wr * 64 + m * 16 + l15) * 32 + lk];
#pragma unroll
    for (int n = 0; n < 4; ++n)
      bF[n] = *(const bf16x8*)&Btile[(wc * 64 + n * 16 + l15) * 32 + lk];
#pragma unroll
    for (int m = 0; m < 4; ++m)
#pragma unroll
      for (int n = 0; n < 4; ++n)
        acc[m][n] = __builtin_amdgcn_mfma_f32_16x16x32_bf16(aF[m], bF[n], acc[m][n], 0, 0, 0);
  }
  const int lr = (lane >> 4) * 4, lc = lane & 15;
  if (BF16OUT) {
    unsigned short* C = (unsigned short*)Cout;
#pragma unroll
    for (int m = 0; m < 4; ++m) {
      int row = brow + wr * 64 + m * 16 + lr;
#pragma unroll
      for (int n = 0; n < 4; ++n) {
        int col = bcol + wc * 64 + n * 16 + lc;
#pragma unroll
        for (int i = 0; i < 4; ++i)
          C[(size_t)(row + i) * N + col] = f2bf(acc[m][n][i]);
      }
    }
  } else {
    float* C = (float*)Cout;
#pragma unroll
    for (int m = 0; m < 4; ++m) {
      int row = brow + wr * 64 + m * 16 + lr;
#pragma unroll
      for (int n = 0; n < 4; ++n) {
        int col = bcol + wc * 64 + n * 16 + lc;
#pragma unroll
        for (int i = 0; i < 4; ++i)
          C[(size_t)(row + i) * N + col] = acc[m][n][i];
      }
    }
  }
}

// ---------------- RoPE in place on QKV [4096][5120] ----------------
__global__ void rope_kernel(unsigned short* __restrict__ QKV, const float* __restrict__ cosT,
                            const float* __restrict__ sinT) {
  int rid = blockIdx.x;
  int s = rid & (Sn - 1);
  unsigned short* row = QKV + (size_t)rid * LDQKV;
  for (int p = threadIdx.x; p < 32 * 48; p += 256) {
    int h = p / 48, i = p % 48;
    int col = (h < NQn) ? h * HDn : KCOLo + (h - NQn) * HDn;
    float c = cosT[s * 48 + i], sn = sinT[s * 48 + i];
    float x1 = bf2f(row[col + i]), x2 = bf2f(row[col + i + 48]);
    row[col + i] = f2bf(x1 * c - x2 * sn);
    row[col + i + 48] = f2bf(x2 * c + x1 * sn);
  }
}

// ---------------- Flash attention (causal, GQA 3:1), double-buffered K/V ----------------
// Swapped-operand QK^T: S = mfma(K, Q) -> lane-local q (col = lane&15) so the
// softmax reduce is in-register + 2 shuffles, and m/l/rescale are scalars.
// grid: (S/64, B*NQ); 256 thr = 4 waves; wave w owns q rows [bq*64+w*16, +16)
__launch_bounds__(256, 2)
__global__ void attn_kernel(const unsigned short* __restrict__ QKV,
                            const unsigned short* __restrict__ VT,
                            unsigned short* __restrict__ O) {
  __shared__ unsigned short Klds[2][64 * 128];  // [kcol][hd] chunks, src pre-swizzled
  __shared__ unsigned short Vlds[2][128 * 64];  // [hd][k] chunks, src pre-swizzled
  __shared__ unsigned short Plds[4][16 * 64];   // per-wave [q][k] swizzled
  const int t = threadIdx.x, lane = t & 63, w = t >> 6;
  const int bq = gridDim.x - 1 - blockIdx.x;  // heavy (many-tile) blocks dispatch first
  const int hid = blockIdx.y;
  const int b = hid / NQn, u = hid % NQn, kv = u / 3;
  const int l15 = lane & 15, lh = lane >> 4;

  bf16x8 qf[4];
  {
    int qrow = bq * 64 + w * 16 + l15;
    const unsigned short* qp = QKV + (size_t)(b * Sn + qrow) * LDQKV + u * HDn;
#pragma unroll
    for (int f = 0; f < 4; ++f) qf[f] = *(const bf16x8*)(qp + f * 32 + lh * 8);
  }
  // lane-local softmax state for q = w*16 + l15 (lanes l15, l15+16, +32, +48 replicate)
  float m_l = -1e30f, l_l = 0.f;
  f32x4 Oa[8] = {};  // O^T: Oa[g][i] = O[q=l15][hd=g*16+lh*4+i]
  const float cscale = 0.08838834764831845f * 1.4426950408889634f;  // 1/sqrt(128)*log2e

  const unsigned short* Kg = QKV + (size_t)(b * Sn) * LDQKV + KCOLo + kv * HDn;
  const unsigned short* Vg = VT + (size_t)(b * NKVn + kv) * HDn * Sn;

  auto stageK = [&](int kt, int buf) {
#pragma unroll
    for (int iter = 0; iter < 4; ++iter) {
      int c = iter * 256 + t;
      int krow = c >> 4, pch = c & 15;
      int hch = (pch & 8) | ((pch & 7) ^ (krow & 7));
      gload_lds16(Kg + (size_t)(kt * 64 + krow) * LDQKV + hch * 8,
                  (char*)&Klds[buf][0] + (iter * 256 + w * 64) * 16);
    }
  };
  auto stageV = [&](int kt, int buf) {
#pragma unroll
    for (int iter = 0; iter < 4; ++iter) {
      int c = iter * 256 + t;
      int hd = c >> 3, p = c & 7;
      int sch = p ^ (hd & 7);
      gload_lds16(Vg + (size_t)hd * Sn + kt * 64 + sch * 8,
                  (char*)&Vlds[buf][0] + (iter * 256 + w * 64) * 16);
    }
  };

  const int nt = bq + 1;
  stageK(0, 0);
  stageV(0, 0);
  __syncthreads();  // drains vmcnt (barrier semantics)

  for (int kt = 0; kt < nt; ++kt) {
    const int cur = kt & 1;
    if (kt + 1 < nt) { stageK(kt + 1, cur ^ 1); stageV(kt + 1, cur ^ 1); }
    const unsigned short* Kb = &Klds[cur][0];
    const unsigned short* Vb = &Vlds[cur][0];
    // QK^T swapped: Sg[g] = S[k=g*16+lh*4+i][q=l15]
    f32x4 Sg[4] = {};
    __builtin_amdgcn_s_setprio(1);
#pragma unroll
    for (int g = 0; g < 4; ++g) {
      int kcol = g * 16 + l15;  // A-row = k
#pragma unroll
      for (int s = 0; s < 4; ++s) {
        int h = s * 4 + lh;
        int p = (h & 8) | ((h & 7) ^ (kcol & 7));
        bf16x8 kf = *(const bf16x8*)&Kb[kcol * 128 + p * 8];
        Sg[g] = __builtin_amdgcn_mfma_f32_16x16x32_bf16(kf, qf[s], Sg[g], 0, 0, 0);
      }
    }
    __builtin_amdgcn_s_setprio(0);
    float P[4][4];
    const bool last = (kt == bq);
    const int qin = w * 16 + l15;
#pragma unroll
    for (int g = 0; g < 4; ++g)
#pragma unroll
      for (int i = 0; i < 4; ++i) {
        float sv = Sg[g][i] * cscale;
        if (last && (g * 16 + lh * 4 + i) > qin) sv = -1e30f;
        P[g][i] = sv;
      }
    // lane-local online softmax (one q per lane)
    float pmax = -1e30f;
#pragma unroll
    for (int g = 0; g < 4; ++g)
#pragma unroll
      for (int i = 0; i < 4; ++i) pmax = fmaxf(pmax, P[g][i]);
    pmax = fmaxf(pmax, __shfl_xor(pmax, 16, 64));
    pmax = fmaxf(pmax, __shfl_xor(pmax, 32, 64));
    float mn = fmaxf(m_l, pmax);
    float rs = exp2f(m_l - mn);
    m_l = mn;
    float ps = 0.f;
#pragma unroll
    for (int g = 0; g < 4; ++g)
#pragma unroll
      for (int i = 0; i < 4; ++i) {
        float e = exp2f(P[g][i] - mn);
        P[g][i] = e;
        ps += e;
      }
    ps += __shfl_xor(ps, 16, 64);
    ps += __shfl_xor(ps, 32, 64);
    l_l = l_l * rs + ps;
#pragma unroll
    for (int g = 0; g < 8; ++g)
#pragma unroll
      for (int i = 0; i < 4; ++i) Oa[g][i] *= rs;
    // P -> per-wave LDS [q=l15][k], packed b64 writes, swizzled by (k>>3)^(q&7)
    unsigned short* pl = Plds[w];
#pragma unroll
    for (int g = 0; g < 4; ++g) {
      int ch = g * 2 + (lh >> 1);
      int pos = ch ^ (l15 & 7);
      u16x4 pk;
#pragma unroll
      for (int i = 0; i < 4; ++i) pk[i] = f2bf(P[g][i]);
      *(u16x4*)&pl[l15 * 64 + pos * 8 + (lh & 1) * 4] = pk;
    }
    // PV swapped: Oa[g] = mfma(V[hd][k], P[k][q]) -> D[hd][q]
    __builtin_amdgcn_s_setprio(1);
#pragma unroll
    for (int kk = 0; kk < 2; ++kk) {
      int ch = kk * 4 + lh;
      bf16x8 pf = *(const bf16x8*)&pl[l15 * 64 + ((ch ^ (l15 & 7)) & 7) * 8];
#pragma unroll
      for (int g = 0; g < 8; ++g) {
        int hd = g * 16 + l15;
        int vpos = (ch ^ (hd & 7)) & 7;
        bf16x8 vf = *(const bf16x8*)&Vb[hd * 64 + vpos * 8];
        Oa[g] = __builtin_amdgcn_mfma_f32_16x16x32_bf16(vf, pf, Oa[g], 0, 0, 0);
      }
    }
    __builtin_amdgcn_s_setprio(0);
    __syncthreads();  // all waves done with buf cur; next-tile loads drained
  }
  // Epilogue: O^T -> O through per-wave scratch in (dead) Klds, coalesced store.
  // All waves passed the loop's final __syncthreads(); scratch regions are per-wave.
  {
    unsigned short* sc = (unsigned short*)Klds + w * 2176;  // [16 q][136 hd] padded
    float inv = 1.0f / l_l;
#pragma unroll
    for (int g = 0; g < 8; ++g)
#pragma unroll
      for (int i = 0; i < 4; ++i)
        sc[l15 * 136 + g * 16 + lh * 4 + i] = f2bf(Oa[g][i] * inv);
    int q = lane >> 2, a = lane & 3;
    int row = bq * 64 + w * 16 + q;
    unsigned short* op = O + (size_t)(b * Sn + row) * (NQn * HDn) + u * HDn;
    const unsigned short* scr = sc + q * 136;
#pragma unroll
    for (int j = 0; j < 4; ++j) {
      bf16x8 v = *(const bf16x8*)&scr[a * 8 + j * 32];
      *(bf16x8*)&op[a * 8 + j * 32] = v;
    }
  }
}

}  // namespace

extern "C" void kernel_launch(void* const* d_in, const int* in_sizes, int n_in,
                              void* d_out, int out_size, void* d_ws, size_t ws_size,
                              hipStream_t stream) {
  const float* hidden = (const float*)d_in[0];
  // d_in[1] = attention_mask (causal tril) -- implemented analytically
  const float* Wq = (const float*)d_in[2];
  const float* Wk = (const float*)d_in[3];
  const float* Wv = (const float*)d_in[4];
  const float* Wo = (const float*)d_in[5];
  float* out = (float*)d_out;

  // Workspace layout (aliased; same-stream ordering makes each alias safe):
  //   [0)           Xb   (25.2MB)  -- dead after GEMM1; Obuf aliases it
  //   [szXb)        Wqkv (31.5MB)  -- dead after GEMM1; Wob (18.9MB) + VT (8.4MB) alias it
  //   [szXb+szWqkv) QKV  (41.9MB)
  //   [+szQKV)      cosT/sinT (0.8MB)
  char* ws = (char*)d_ws;
  constexpr size_t szXb = (size_t)Bn * Sn * Hn * 2;             // 25165824
  constexpr size_t szWqkv = (size_t)LDQKV * Hn * 2;             // 31457280
  constexpr size_t szWo = (size_t)Hn * Hn * 2;                  // 18874368
  constexpr size_t szVT = (size_t)Bn * NKVn * HDn * Sn * 2;     // 8388608
  constexpr size_t szQKV = (size_t)Bn * Sn * LDQKV * 2;         // 41943040
  constexpr size_t szTab = (size_t)Sn * 48 * 4;                 // 393216
  static_assert(szWo + szVT <= szWqkv, "Wob+VT must fit in Wqkv region");
  constexpr size_t szTotal = szXb + szWqkv + szQKV + 2 * szTab; // 99352576
  if (ws_size < szTotal) return;  // fail cleanly, don't fault

  unsigned short* Xb = (unsigned short*)(ws);
  unsigned short* Obuf = Xb;                                  // alias
  unsigned short* Wqkv = (unsigned short*)(ws + szXb);
  unsigned short* Wob = Wqkv;                                 // alias (after GEMM1)
  unsigned short* VT = (unsigned short*)(ws + szXb + szWo);   // alias (after GEMM1)
  unsigned short* QKV = (unsigned short*)(ws + szXb + szWqkv);
  float* cosT = (float*)(ws + szXb + szWqkv + szQKV);
  float* sinT = (float*)(ws + szXb + szWqkv + szQKV + szTab);

  build_rope_tab<<<(Sn * 48 + 255) / 256, 256, 0, stream>>>(cosT, sinT);
  cvt_f32_bf16<<<3072, 256, 0, stream>>>(hidden, Xb, Bn * Sn * Hn);
  transpose_cvt<<<dim3(96, 96), 256, 0, stream>>>(Wq, Wqkv, Hn, NQn * HDn);
  transpose_cvt<<<dim3(32, 96), 256, 0, stream>>>(Wk, Wqkv + (size_t)KCOLo * Hn, Hn, NKVn * HDn);
  transpose_cvt<<<dim3(32, 96), 256, 0, stream>>>(Wv, Wqkv + (size_t)VCOLo * Hn, Hn, NKVn * HDn);
  gemm_tn<1><<<dim3(LDQKV / 128, (Bn * Sn) / 128), 256, 0, stream>>>(Xb, Wqkv, QKV,
                                                                    Bn * Sn, LDQKV, Hn);
  // Wqkv and Xb are now dead; reuse their space.
  transpose_cvt<<<dim3(96, 96), 256, 0, stream>>>(Wo, Wob, Hn, Hn);
  transpose_v<<<dim3(Sn / 32, Bn * NKVn * HDn / 32), 256, 0, stream>>>(QKV, VT);
  rope_kernel<<<Bn * Sn, 256, 0, stream>>>(QKV, cosT, sinT);
  attn_kernel<<<dim3(Sn / 64, Bn * NQn), 256, 0, stream>>>(QKV, VT, Obuf);
  gemm_tn<0><<<dim3(Hn / 128, (Bn * Sn) / 128), 256, 0, stream>>>(Obuf, Wob, out,
                                                                  Bn * Sn, Hn, Hn);
}